// Round 1
// baseline (626.201 us; speedup 1.0000x reference)
//
#include <hip/hip_runtime.h>
#include <math.h>

#define L_SEQ 1024
#define DM 128
#define JC 64
#define NCH (L_SEQ / JC)

// workspace layout (floats)
#define OFF_KHAT 0                         // [L][4][48]  slots: 0..31 K, 32..43 Kg, 44 ck, 45 1.0, 46..47 0
#define OFF_QHAT (L_SEQ * 192)             // [L][4][48]  slots: 0..31 scale*Q, 32..43 w*Qg, 44 1.0, 45 cq
#define OFF_V    (OFF_QHAT + L_SEQ * 192)  // [L][128]    (h*32+d)
#define OFF_VG   (OFF_V + L_SEQ * DM)      // [L][48]     (h*12+p*3+x)

typedef __attribute__((address_space(1))) const void* gas_t;
typedef __attribute__((address_space(3))) void* las_t;

__device__ __forceinline__ void async16(const float4* g, float4* l) {
    __builtin_amdgcn_global_load_lds((gas_t)g, (las_t)l, 16, 0, 0);
}
// raw barrier: drain LDS ops only; do NOT drain vmcnt (keeps async prefetch in flight)
#define ASYNC_BAR() asm volatile("s_waitcnt lgkmcnt(0)\n\ts_barrier" ::: "memory")

// ---------------- kernel 1: LN + projections + rotations + staging ----------------
__global__ __launch_bounds__(256) void ipa_prep(
    const float* __restrict__ single, const float* __restrict__ T,
    const float* __restrict__ w_C, const float* __restrict__ ln_g, const float* __restrict__ ln_b,
    const float* __restrict__ Wq, const float* __restrict__ Wk, const float* __restrict__ Wv,
    const float* __restrict__ Wqpt, const float* __restrict__ Wkpt, const float* __restrict__ Wvpt,
    float* __restrict__ ws)
{
    __shared__ float z_lds[4][128];
    __shared__ float proj[4][528];
    __shared__ float qg[4][4][4][3];
    __shared__ float kg[4][4][4][3];
    __shared__ float cq[4][4], ck[4][4];

    const int t = threadIdx.x;
    const int wv = t >> 6, lane = t & 63;
    const int i0 = blockIdx.x << 2;
    const int i = i0 + wv;

    float x0 = single[i*DM + lane];
    float x1 = single[i*DM + 64 + lane];
    float s = x0 + x1, s2 = x0*x0 + x1*x1;
    #pragma unroll
    for (int off = 1; off < 64; off <<= 1) { s += __shfl_xor(s, off); s2 += __shfl_xor(s2, off); }
    float mu = s * 0.0078125f;
    float var = s2 * 0.0078125f - mu*mu;
    float rs = rsqrtf(var + 1e-5f);
    z_lds[wv][lane]      = (x0 - mu) * rs * ln_g[lane]      + ln_b[lane];
    z_lds[wv][lane + 64] = (x1 - mu) * rs * ln_g[lane + 64] + ln_b[lane + 64];
    __syncthreads();

    for (int cc = t; cc < 528; cc += 256) {
        const float* W; int col, ncol;
        if (cc < 128)      { W = Wq;   col = cc;       ncol = 128; }
        else if (cc < 256) { W = Wk;   col = cc - 128; ncol = 128; }
        else if (cc < 384) { W = Wv;   col = cc - 256; ncol = 128; }
        else if (cc < 432) { W = Wqpt; col = cc - 384; ncol = 48;  }
        else if (cc < 480) { W = Wkpt; col = cc - 432; ncol = 48;  }
        else               { W = Wvpt; col = cc - 480; ncol = 48;  }
        float a0 = 0.f, a1 = 0.f, a2 = 0.f, a3 = 0.f;
        #pragma unroll 8
        for (int k = 0; k < 128; ++k) {
            float w = W[k*ncol + col];
            a0 = fmaf(z_lds[0][k], w, a0);
            a1 = fmaf(z_lds[1][k], w, a1);
            a2 = fmaf(z_lds[2][k], w, a2);
            a3 = fmaf(z_lds[3][k], w, a3);
        }
        proj[0][cc] = a0; proj[1][cc] = a1; proj[2][cc] = a2; proj[3][cc] = a3;
    }
    __syncthreads();

    if (t < 64) {
        int r = t >> 4, h = (t >> 2) & 3, p = t & 3;
        int ii = i0 + r;
        float R[3][3], tt[3];
        #pragma unroll
        for (int x = 0; x < 3; ++x) {
            #pragma unroll
            for (int y = 0; y < 3; ++y) R[x][y] = T[ii*16 + x*4 + y];
            tt[x] = T[ii*16 + x*4 + 3];
        }
        int base = 384 + (h*4 + p)*3;
        float q0 = proj[r][base],    q1 = proj[r][base+1],  q2 = proj[r][base+2];
        float k0 = proj[r][base+48], k1 = proj[r][base+49], k2 = proj[r][base+50];
        float v0 = proj[r][base+96], v1 = proj[r][base+97], v2 = proj[r][base+98];
        #pragma unroll
        for (int x = 0; x < 3; ++x) {
            float qq = R[x][0]*q0 + R[x][1]*q1 + R[x][2]*q2 + tt[x];
            float kk = R[x][0]*k0 + R[x][1]*k1 + R[x][2]*k2 + tt[x];
            float vv = R[x][0]*v0 + R[x][1]*v1 + R[x][2]*v2 + tt[x];
            qg[r][h][p][x] = qq;
            kg[r][h][p][x] = kk;
            ws[OFF_VG + ii*48 + h*12 + p*3 + x] = vv;
        }
    }
    __syncthreads();

    if (t < 32) {
        int r = t >> 3, h = (t >> 1) & 3, isk = t & 1;
        float w = w_C[h];
        float wp = log1pf(__expf(w));
        float sq = 0.f;
        #pragma unroll
        for (int p = 0; p < 4; ++p)
            #pragma unroll
            for (int x = 0; x < 3; ++x) {
                float g = isk ? kg[r][h][p][x] : qg[r][h][p][x];
                sq += g*g;
            }
        float c = -0.5f * wp * sq;
        if (isk) ck[r][h] = c; else cq[r][h] = c;
    }
    __syncthreads();

    for (int idx = t; idx < 512; idx += 256) {
        int r = idx >> 7, d = idx & 127;
        ws[OFF_V + (size_t)(i0 + r)*DM + d] = proj[r][256 + d];
    }
    const float scale_attn = 0.17677669529663687f;  // 32^-0.5
    for (int idx = t; idx < 768; idx += 256) {
        int r = idx / 192, rem = idx % 192;
        int h = rem / 48, k = rem % 48;
        int ii = i0 + r;
        float w = w_C[h];
        float wp = log1pf(__expf(w));
        float kv, qv;
        if (k < 32) {
            kv = proj[r][128 + h*32 + k];
            qv = scale_attn * proj[r][h*32 + k];
        } else if (k < 44) {
            int e = k - 32;
            kv = kg[r][h][e/3][e%3];
            qv = wp * qg[r][h][e/3][e%3];
        } else if (k == 44) { kv = ck[r][h]; qv = 1.0f; }
        else if (k == 45)   { kv = 1.0f;    qv = cq[r][h]; }
        else                { kv = 0.f;     qv = 0.f; }
        ws[OFF_KHAT + (size_t)ii*192 + h*48 + k] = kv;
        ws[OFF_QHAT + (size_t)ii*192 + h*48 + k] = qv;
    }
}

// ---------------- kernel 2: fused IPA attention, 1 row/block, grid=1024 (4 blocks/CU resident) ----------------
__global__ __launch_bounds__(256, 4) void ipa_attn(
    const float* __restrict__ single, const float* __restrict__ pair,
    const float* __restrict__ T, const float* __restrict__ Wb,
    const float* __restrict__ Wout, const float* __restrict__ b_out,
    const float* __restrict__ ws, float* __restrict__ out)
{
    // LDS budget: 32768 + 5120 + 1024 + 16 + 16 + 768 + 1024 = 40736 B -> 4 blocks/CU
    __shared__ __align__(16) float4 pair_lds[2][JC][16]; // [buf][j][slot] swizzled slot=c4^(j&7), 32 KB
    __shared__ float bias_part[4][JC][5];                // [c-quarter][j][h] pad 5 (conflict-free strided reads)
    __shared__ __align__(16) float4 p4_lds[JC];          // p[j][h] as float4 per j
    __shared__ float alpha_lds[4];
    __shared__ float l_lds[4];
    __shared__ __align__(16) float4 qhat_lds[4][12];
    __shared__ __align__(16) float4 wb_lds[64];

    const int t = threadIdx.x;
    const int wv = t >> 6, lane = t & 63;
    const int i = blockIdx.x;

    if (t < 48)       ((float4*)qhat_lds)[t] = ((const float4*)(ws + OFF_QHAT))[(size_t)i*48 + t];
    else if (t < 112) wb_lds[t - 48] = ((const float4*)Wb)[t - 48];

    // phase-role indices
    const int d4  = lane & 7,  jg_s = lane >> 3;  // o_s
    const int c4p = lane >> 4, jg_p = lane & 15;  // o_pair
    const int g4  = lane & 3,  jg_g = lane >> 2;  // o_pt_g
    const int g4c = (g4 < 3) ? g4 : 0;
    const int c4o = wv << 2;                      // wave's c-quarter base

    float m_run = -INFINITY, l_run = 0.f;
    float alpha_own = 0.f;
    float4 accp[4];   // o_pair: c4 = c4o + c4p, per head
    float4 accs;      // o_s: head wv, d = d4*4+e, j-split by jg_s
    float4 accg;      // o_pt_g: head wv, group g4c, j-split by jg_g
    accs = make_float4(0.f,0.f,0.f,0.f);
    accg = make_float4(0.f,0.f,0.f,0.f);
    #pragma unroll
    for (int h = 0; h < 4; ++h) accp[h] = make_float4(0.f,0.f,0.f,0.f);

    const float4* pair4 = (const float4*)pair;
    const float4* kh4   = (const float4*)(ws + OFF_KHAT);
    const float4* v4    = (const float4*)(ws + OFF_V);
    const float4* vg4   = (const float4*)(ws + OFF_VG);
    float4* plds_flat   = &pair_lds[0][0][0];
    float*  p_s         = (float*)p4_lds;

    // issue chunk 0 -> buf 0 (4 async16/thread; LDS dest lane-linear, global swizzle-permuted)
    #pragma unroll
    for (int it = 0; it < 4; ++it) {
        int idx = it*256 + t;
        int j = idx >> 4, slot = idx & 15;
        int c4 = slot ^ (j & 7);
        async16(pair4 + ((size_t)i*L_SEQ + j)*16 + c4, plds_flat + idx);
    }

    for (int ch = 0; ch < NCH; ++ch) {
        const int cur = ch & 1;
        const int j0 = ch * JC;

        ASYNC_BAR();   // prev iter's reads of buf[1-cur] done; (ch=0: qhat/wb published)
        if (ch + 1 < NCH) {
            const int jn = (ch + 1) * JC;
            #pragma unroll
            for (int it = 0; it < 4; ++it) {
                int idx = it*256 + t;
                int j = idx >> 4, slot = idx & 15;
                int c4 = slot ^ (j & 7);
                async16(pair4 + ((size_t)i*L_SEQ + jn + j)*16 + c4,
                        plds_flat + (1 - cur)*1024 + idx);
            }
            asm volatile("s_waitcnt vmcnt(4)" ::: "memory");   // drain chunk ch, keep ch+1 in flight
        } else {
            asm volatile("s_waitcnt vmcnt(0)" ::: "memory");
        }
        ASYNC_BAR();   // buf[cur] visible to all waves

        // early-issue kh loads (head wv, row j0+lane) — overlap with phase B
        float4 kh[12];
        {
            const float4* kp = kh4 + (size_t)(j0 + lane)*48 + wv*12;
            #pragma unroll
            for (int k4 = 0; k4 < 12; ++k4) kh[k4] = kp[k4];
        }

        // ---- phase B: bias partials; wave wv covers c-quarter for its j=lane ----
        {
            float bx=0.f, by=0.f, bz=0.f, bw=0.f;
            #pragma unroll
            for (int cp = 0; cp < 4; ++cp) {
                int c4 = c4o + cp;
                int sw = c4 ^ (lane & 7);
                float4 pv = pair_lds[cur][lane][sw];
                float4 w0 = wb_lds[c4*4+0], w1 = wb_lds[c4*4+1], w2 = wb_lds[c4*4+2], w3 = wb_lds[c4*4+3];
                bx += pv.x*w0.x + pv.y*w1.x + pv.z*w2.x + pv.w*w3.x;
                by += pv.x*w0.y + pv.y*w1.y + pv.z*w2.y + pv.w*w3.y;
                bz += pv.x*w0.z + pv.y*w1.z + pv.z*w2.z + pv.w*w3.z;
                bw += pv.x*w0.w + pv.y*w1.w + pv.z*w2.w + pv.w*w3.w;
            }
            bias_part[wv][lane][0] = bx; bias_part[wv][lane][1] = by;
            bias_part[wv][lane][2] = bz; bias_part[wv][lane][3] = bw;
        }
        ASYNC_BAR();

        float4 vv[8];   // o_s V tiles (issued mid-S, consumed in A)
        float4 gvv[4];  // o_pt_g VG tiles

        // ---- phase S: logit (48-dot) + bias + online softmax (lane = j, head wv) ----
        {
            float d = 0.f;
            #pragma unroll
            for (int k4 = 0; k4 < 12; ++k4) {
                float4 q = qhat_lds[wv][k4];
                d = fmaf(kh[k4].x, q.x, d); d = fmaf(kh[k4].y, q.y, d);
                d = fmaf(kh[k4].z, q.z, d); d = fmaf(kh[k4].w, q.w, d);
            }
            float bias = bias_part[0][lane][wv] + bias_part[1][lane][wv]
                       + bias_part[2][lane][wv] + bias_part[3][lane][wv];
            float logit = d + bias;

            // issue phase-A global loads now (independent of softmax chain; kh dead -> regs reused)
            #pragma unroll
            for (int jj = 0; jj < 8; ++jj)
                vv[jj] = v4[(size_t)(j0 + jg_s + 8*jj)*32 + wv*8 + d4];
            #pragma unroll
            for (int jj = 0; jj < 4; ++jj)
                gvv[jj] = vg4[(size_t)(j0 + jg_g + 16*jj)*12 + wv*3 + g4c];

            float cmax = logit;
            #pragma unroll
            for (int off = 1; off < 64; off <<= 1) cmax = fmaxf(cmax, __shfl_xor(cmax, off));
            float mn = fmaxf(m_run, cmax);
            float alpha = __expf(m_run - mn);
            float p = __expf(logit - mn);
            l_run = l_run * alpha + p;     // per-lane partial l (own j's only); reduced at end
            m_run = mn;
            alpha_own = alpha;
            p_s[lane*4 + wv] = p;
            if (lane == 0) alpha_lds[wv] = alpha;
        }
        ASYNC_BAR();

        // ---- phase A: rescale + accumulate ----
        {
            float al0 = alpha_lds[0], al1 = alpha_lds[1], al2 = alpha_lds[2], al3 = alpha_lds[3];
            accp[0].x *= al0; accp[0].y *= al0; accp[0].z *= al0; accp[0].w *= al0;
            accp[1].x *= al1; accp[1].y *= al1; accp[1].z *= al1; accp[1].w *= al1;
            accp[2].x *= al2; accp[2].y *= al2; accp[2].z *= al2; accp[2].w *= al2;
            accp[3].x *= al3; accp[3].y *= al3; accp[3].z *= al3; accp[3].w *= al3;
            accs.x *= alpha_own; accs.y *= alpha_own; accs.z *= alpha_own; accs.w *= alpha_own;
            accg.x *= alpha_own; accg.y *= alpha_own; accg.z *= alpha_own; accg.w *= alpha_own;

            // o_pair: c4 = c4o + c4p, j = jg_p + 16*jj
            {
                int c4 = c4o + c4p;
                #pragma unroll
                for (int jj = 0; jj < 4; ++jj) {
                    int j = jg_p + 16*jj;
                    int sw = c4 ^ (j & 7);
                    float4 pv = pair_lds[cur][j][sw];
                    float4 pj = p4_lds[j];
                    accp[0].x = fmaf(pj.x, pv.x, accp[0].x); accp[0].y = fmaf(pj.x, pv.y, accp[0].y);
                    accp[0].z = fmaf(pj.x, pv.z, accp[0].z); accp[0].w = fmaf(pj.x, pv.w, accp[0].w);
                    accp[1].x = fmaf(pj.y, pv.x, accp[1].x); accp[1].y = fmaf(pj.y, pv.y, accp[1].y);
                    accp[1].z = fmaf(pj.y, pv.z, accp[1].z); accp[1].w = fmaf(pj.y, pv.w, accp[1].w);
                    accp[2].x = fmaf(pj.z, pv.x, accp[2].x); accp[2].y = fmaf(pj.z, pv.y, accp[2].y);
                    accp[2].z = fmaf(pj.z, pv.z, accp[2].z); accp[2].w = fmaf(pj.z, pv.w, accp[2].w);
                    accp[3].x = fmaf(pj.w, pv.x, accp[3].x); accp[3].y = fmaf(pj.w, pv.y, accp[3].y);
                    accp[3].z = fmaf(pj.w, pv.z, accp[3].z); accp[3].w = fmaf(pj.w, pv.w, accp[3].w);
                }
            }
            // o_s: head wv
            #pragma unroll
            for (int jj = 0; jj < 8; ++jj) {
                int j = jg_s + 8*jj;
                float pa = p_s[j*4 + wv];
                accs.x = fmaf(pa, vv[jj].x, accs.x); accs.y = fmaf(pa, vv[jj].y, accs.y);
                accs.z = fmaf(pa, vv[jj].z, accs.z); accs.w = fmaf(pa, vv[jj].w, accs.w);
            }
            // o_pt_g: head wv
            #pragma unroll
            for (int jj = 0; jj < 4; ++jj) {
                int j = jg_g + 16*jj;
                float pa = p_s[j*4 + wv];
                accg.x = fmaf(pa, gvv[jj].x, accg.x); accg.y = fmaf(pa, gvv[jj].y, accg.y);
                accg.z = fmaf(pa, gvv[jj].z, accg.z); accg.w = fmaf(pa, gvv[jj].w, accg.w);
            }
        }
    }

    // ---- epilogue ----
    #pragma unroll
    for (int h = 0; h < 4; ++h) {
        #pragma unroll
        for (int off = 1; off < 16; off <<= 1) {   // reduce over jg_p = lane&15
            accp[h].x += __shfl_xor(accp[h].x, off);
            accp[h].y += __shfl_xor(accp[h].y, off);
            accp[h].z += __shfl_xor(accp[h].z, off);
            accp[h].w += __shfl_xor(accp[h].w, off);
        }
    }
    #pragma unroll
    for (int off = 8; off < 64; off <<= 1) {       // reduce over jg_s
        accs.x += __shfl_xor(accs.x, off); accs.y += __shfl_xor(accs.y, off);
        accs.z += __shfl_xor(accs.z, off); accs.w += __shfl_xor(accs.w, off);
    }
    #pragma unroll
    for (int off = 4; off < 64; off <<= 1) {       // reduce over jg_g
        accg.x += __shfl_xor(accg.x, off); accg.y += __shfl_xor(accg.y, off);
        accg.z += __shfl_xor(accg.z, off); accg.w += __shfl_xor(accg.w, off);
    }
    #pragma unroll
    for (int off = 1; off < 64; off <<= 1)         // reduce l over all lanes
        l_run += __shfl_xor(l_run, off);
    if (lane == 0) l_lds[wv] = l_run;
    __syncthreads();                                // also: all pair_lds reads done -> safe to alias

    // epilogue scratch aliased over pair staging region
    float* scratch = (float*)&pair_lds[0][0][0];
    float* u   = scratch;          // [448] concat buffer
    float* og  = scratch + 448;    // [4][12]
    float* tmp = scratch + 512;    // [128] split-k partial

    float invl[4];
    #pragma unroll
    for (int h = 0; h < 4; ++h) invl[h] = 1.f / l_lds[h];

    if (lane < 8) {
        float sc = invl[wv];
        int base = wv*32 + lane*4;
        u[base+0] = accs.x*sc; u[base+1] = accs.y*sc;
        u[base+2] = accs.z*sc; u[base+3] = accs.w*sc;
    }
    if ((lane & 15) == 0) {
        int c4 = c4o + (lane >> 4);
        #pragma unroll
        for (int h = 0; h < 4; ++h) {
            float sc = invl[h];
            int base = 128 + h*64 + c4*4;
            u[base+0] = accp[h].x*sc; u[base+1] = accp[h].y*sc;
            u[base+2] = accp[h].z*sc; u[base+3] = accp[h].w*sc;
        }
    }
    if (lane < 3) {
        float sc = invl[wv];
        og[wv*12 + lane*4+0] = accg.x*sc; og[wv*12 + lane*4+1] = accg.y*sc;
        og[wv*12 + lane*4+2] = accg.z*sc; og[wv*12 + lane*4+3] = accg.w*sc;
    }
    __syncthreads();

    if (t < 16) {
        int h = t >> 2, p = t & 3;
        float R[3][3], tt[3];
        #pragma unroll
        for (int x = 0; x < 3; ++x) {
            #pragma unroll
            for (int y = 0; y < 3; ++y) R[x][y] = T[i*16 + x*4 + y];
            tt[x] = T[i*16 + x*4 + 3];
        }
        float v0 = og[h*12 + p*3+0] - tt[0];
        float v1 = og[h*12 + p*3+1] - tt[1];
        float v2 = og[h*12 + p*3+2] - tt[2];
        float n2 = 0.f;
        #pragma unroll
        for (int x = 0; x < 3; ++x) {
            float o = R[0][x]*v0 + R[1][x]*v1 + R[2][x]*v2;
            u[384 + h*12 + p*3 + x] = o;
            n2 += o*o;
        }
        u[432 + h*4 + p] = sqrtf(n2);
    }
    __syncthreads();

    // final matmul, split-k across thread halves (both halves busy)
    {
        int d = t & 127, khalf = t >> 7;
        float acc = 0.f;
        const float4* u4 = (const float4*)u;
        int k0 = khalf * 56;
        #pragma unroll 4
        for (int k4 = k0; k4 < k0 + 56; ++k4) {
            float4 uu = u4[k4];
            const float* wp = Wout + (size_t)(k4*4)*128 + d;
            acc = fmaf(uu.x, wp[0],   acc);
            acc = fmaf(uu.y, wp[128], acc);
            acc = fmaf(uu.z, wp[256], acc);
            acc = fmaf(uu.w, wp[384], acc);
        }
        if (khalf) tmp[d] = acc;
        __syncthreads();
        if (!khalf) out[i*DM + d] = single[i*DM + d] + b_out[d] + acc + tmp[d];
    }
}

extern "C" void kernel_launch(void* const* d_in, const int* in_sizes, int n_in,
                              void* d_out, int out_size, void* d_ws, size_t ws_size,
                              hipStream_t stream)
{
    const float* single = (const float*)d_in[0];
    const float* pair   = (const float*)d_in[1];
    const float* T      = (const float*)d_in[2];
    const float* w_C    = (const float*)d_in[3];
    const float* ln_g   = (const float*)d_in[4];
    const float* ln_b   = (const float*)d_in[5];
    const float* Wq     = (const float*)d_in[6];
    const float* Wk     = (const float*)d_in[7];
    const float* Wv     = (const float*)d_in[8];
    const float* Wqpt   = (const float*)d_in[9];
    const float* Wkpt   = (const float*)d_in[10];
    const float* Wvpt   = (const float*)d_in[11];
    const float* Wb     = (const float*)d_in[12];
    const float* Wout   = (const float*)d_in[13];
    const float* b_out  = (const float*)d_in[14];
    float* out = (float*)d_out;
    float* ws  = (float*)d_ws;

    ipa_prep<<<256, 256, 0, stream>>>(single, T, w_C, ln_g, ln_b, Wq, Wk, Wv, Wqpt, Wkpt, Wvpt, ws);
    ipa_attn<<<1024, 256, 0, stream>>>(single, pair, T, Wb, Wout, b_out, ws, out);
}

// Round 2
// 541.502 us; speedup vs baseline: 1.1564x; 1.1564x over previous
//
#include <hip/hip_runtime.h>
#include <math.h>

#define L_SEQ 1024
#define DM 128
#define JC 32
#define NCH (L_SEQ / JC)

// workspace layout (floats)
#define OFF_KHAT 0                         // [L][4][48]  slots: 0..31 K, 32..43 Kg, 44 ck, 45 1.0, 46..47 0
#define OFF_QHAT (L_SEQ * 192)             // [L][4][48]  slots: 0..31 scale*Q, 32..43 w*Qg, 44 1.0, 45 cq
#define OFF_V    (OFF_QHAT + L_SEQ * 192)  // [L][128]    (h*32+d)
#define OFF_VG   (OFF_V + L_SEQ * DM)      // [L][48]     (h*12+p*3+x)

typedef __attribute__((address_space(1))) const void* gas_t;
typedef __attribute__((address_space(3))) void* las_t;

__device__ __forceinline__ void async16(const float4* g, float4* l) {
    __builtin_amdgcn_global_load_lds((gas_t)g, (las_t)l, 16, 0, 0);
}
// raw barrier: drain LDS ops only; do NOT drain vmcnt (keeps async prefetch in flight)
#define ASYNC_BAR() asm volatile("s_waitcnt lgkmcnt(0)\n\ts_barrier" ::: "memory")

// ---------------- kernel 1: LN + projections + rotations + staging ----------------
__global__ __launch_bounds__(256) void ipa_prep(
    const float* __restrict__ single, const float* __restrict__ T,
    const float* __restrict__ w_C, const float* __restrict__ ln_g, const float* __restrict__ ln_b,
    const float* __restrict__ Wq, const float* __restrict__ Wk, const float* __restrict__ Wv,
    const float* __restrict__ Wqpt, const float* __restrict__ Wkpt, const float* __restrict__ Wvpt,
    float* __restrict__ ws)
{
    __shared__ float z_lds[4][128];
    __shared__ float proj[4][528];
    __shared__ float qg[4][4][4][3];
    __shared__ float kg[4][4][4][3];
    __shared__ float cq[4][4], ck[4][4];

    const int t = threadIdx.x;
    const int wv = t >> 6, lane = t & 63;
    const int i0 = blockIdx.x << 2;
    const int i = i0 + wv;

    float x0 = single[i*DM + lane];
    float x1 = single[i*DM + 64 + lane];
    float s = x0 + x1, s2 = x0*x0 + x1*x1;
    #pragma unroll
    for (int off = 1; off < 64; off <<= 1) { s += __shfl_xor(s, off); s2 += __shfl_xor(s2, off); }
    float mu = s * 0.0078125f;
    float var = s2 * 0.0078125f - mu*mu;
    float rs = rsqrtf(var + 1e-5f);
    z_lds[wv][lane]      = (x0 - mu) * rs * ln_g[lane]      + ln_b[lane];
    z_lds[wv][lane + 64] = (x1 - mu) * rs * ln_g[lane + 64] + ln_b[lane + 64];
    __syncthreads();

    for (int cc = t; cc < 528; cc += 256) {
        const float* W; int col, ncol;
        if (cc < 128)      { W = Wq;   col = cc;       ncol = 128; }
        else if (cc < 256) { W = Wk;   col = cc - 128; ncol = 128; }
        else if (cc < 384) { W = Wv;   col = cc - 256; ncol = 128; }
        else if (cc < 432) { W = Wqpt; col = cc - 384; ncol = 48;  }
        else if (cc < 480) { W = Wkpt; col = cc - 432; ncol = 48;  }
        else               { W = Wvpt; col = cc - 480; ncol = 48;  }
        float a0 = 0.f, a1 = 0.f, a2 = 0.f, a3 = 0.f;
        #pragma unroll 8
        for (int k = 0; k < 128; ++k) {
            float w = W[k*ncol + col];
            a0 = fmaf(z_lds[0][k], w, a0);
            a1 = fmaf(z_lds[1][k], w, a1);
            a2 = fmaf(z_lds[2][k], w, a2);
            a3 = fmaf(z_lds[3][k], w, a3);
        }
        proj[0][cc] = a0; proj[1][cc] = a1; proj[2][cc] = a2; proj[3][cc] = a3;
    }
    __syncthreads();

    if (t < 64) {
        int r = t >> 4, h = (t >> 2) & 3, p = t & 3;
        int ii = i0 + r;
        float R[3][3], tt[3];
        #pragma unroll
        for (int x = 0; x < 3; ++x) {
            #pragma unroll
            for (int y = 0; y < 3; ++y) R[x][y] = T[ii*16 + x*4 + y];
            tt[x] = T[ii*16 + x*4 + 3];
        }
        int base = 384 + (h*4 + p)*3;
        float q0 = proj[r][base],    q1 = proj[r][base+1],  q2 = proj[r][base+2];
        float k0 = proj[r][base+48], k1 = proj[r][base+49], k2 = proj[r][base+50];
        float v0 = proj[r][base+96], v1 = proj[r][base+97], v2 = proj[r][base+98];
        #pragma unroll
        for (int x = 0; x < 3; ++x) {
            float qq = R[x][0]*q0 + R[x][1]*q1 + R[x][2]*q2 + tt[x];
            float kk = R[x][0]*k0 + R[x][1]*k1 + R[x][2]*k2 + tt[x];
            float vv = R[x][0]*v0 + R[x][1]*v1 + R[x][2]*v2 + tt[x];
            qg[r][h][p][x] = qq;
            kg[r][h][p][x] = kk;
            ws[OFF_VG + ii*48 + h*12 + p*3 + x] = vv;
        }
    }
    __syncthreads();

    if (t < 32) {
        int r = t >> 3, h = (t >> 1) & 3, isk = t & 1;
        float w = w_C[h];
        float wp = log1pf(__expf(w));
        float sq = 0.f;
        #pragma unroll
        for (int p = 0; p < 4; ++p)
            #pragma unroll
            for (int x = 0; x < 3; ++x) {
                float g = isk ? kg[r][h][p][x] : qg[r][h][p][x];
                sq += g*g;
            }
        float c = -0.5f * wp * sq;
        if (isk) ck[r][h] = c; else cq[r][h] = c;
    }
    __syncthreads();

    for (int idx = t; idx < 512; idx += 256) {
        int r = idx >> 7, d = idx & 127;
        ws[OFF_V + (size_t)(i0 + r)*DM + d] = proj[r][256 + d];
    }
    const float scale_attn = 0.17677669529663687f;  // 32^-0.5
    for (int idx = t; idx < 768; idx += 256) {
        int r = idx / 192, rem = idx % 192;
        int h = rem / 48, k = rem % 48;
        int ii = i0 + r;
        float w = w_C[h];
        float wp = log1pf(__expf(w));
        float kv, qv;
        if (k < 32) {
            kv = proj[r][128 + h*32 + k];
            qv = scale_attn * proj[r][h*32 + k];
        } else if (k < 44) {
            int e = k - 32;
            kv = kg[r][h][e/3][e%3];
            qv = wp * qg[r][h][e/3][e%3];
        } else if (k == 44) { kv = ck[r][h]; qv = 1.0f; }
        else if (k == 45)   { kv = 1.0f;    qv = cq[r][h]; }
        else                { kv = 0.f;     qv = 0.f; }
        ws[OFF_KHAT + (size_t)ii*192 + h*48 + k] = kv;
        ws[OFF_QHAT + (size_t)ii*192 + h*48 + k] = qv;
    }
}

// ---------------- kernel 2: fused IPA attention, 1 row/block, JC=32, 2 barriers/chunk ----------------
// Live-register budget: kh[6]=24 (phase S) / vv[4]+gvv[2]=24 (phase A) + acc 24 -> fits 128 VGPR at 4 blocks/CU.
__global__ __launch_bounds__(256, 2) void ipa_attn(
    const float* __restrict__ single, const float* __restrict__ pair,
    const float* __restrict__ T, const float* __restrict__ Wb,
    const float* __restrict__ Wout, const float* __restrict__ b_out,
    const float* __restrict__ ws, float* __restrict__ out)
{
    // LDS: 16384 + 512 + 16 + 16 + 768 + 1024 = 18720 B -> LDS permits 8 blocks/CU (VGPR/grid bind at 4)
    __shared__ __align__(16) float4 pair_lds[2][JC][16]; // [buf][j][slot], slot = c4 ^ (j&7), 16 KB
    __shared__ __align__(16) float4 p4_lds[JC];          // p[j][h] as float4 per j
    __shared__ float alpha_lds[4];
    __shared__ float l_lds[4];
    __shared__ __align__(16) float4 qhat_lds[4][12];     // [h][k4]
    __shared__ __align__(16) float4 wbt_lds[4][16];      // Wb transposed: [h][c4]

    const int t = threadIdx.x;
    const int wv = t >> 6, lane = t & 63;
    const int i = blockIdx.x;

    if (t < 48) ((float4*)qhat_lds)[t] = ((const float4*)(ws + OFF_QHAT))[(size_t)i*48 + t];
    else if (t < 112) {
        int c = t - 48;
        float4 w = ((const float4*)Wb)[c];     // Wb[c][0..3]
        float* wf = (float*)wbt_lds;
        wf[0*64 + c] = w.x; wf[1*64 + c] = w.y; wf[2*64 + c] = w.z; wf[3*64 + c] = w.w;
    }

    // phase-role indices
    const int j_s  = lane & 31, khalf = lane >> 5;  // phase S: 2 lanes per j, split k/c dims
    const int d4   = lane & 7,  jg_s  = lane >> 3;  // o_s
    const int c4p  = lane >> 4, jg_p  = lane & 15;  // o_pair
    const int g4   = lane & 3,  jg_g  = lane >> 2;  // o_pt_g
    const int g4c  = (g4 < 3) ? g4 : 0;
    const int c4o  = wv << 2;                       // wave's c-quarter base (o_pair)

    float m_run = -INFINITY, l_run = 0.f;
    float alpha_own = 0.f;
    float4 accp[4];   // o_pair: c4 = c4o + c4p, per head
    float4 accs;      // o_s: head wv, d = d4*4+e, j-split by jg_s
    float4 accg;      // o_pt_g: head wv, group g4c, j-split by jg_g
    accs = make_float4(0.f,0.f,0.f,0.f);
    accg = make_float4(0.f,0.f,0.f,0.f);
    #pragma unroll
    for (int h = 0; h < 4; ++h) accp[h] = make_float4(0.f,0.f,0.f,0.f);

    const float4* pair4 = (const float4*)pair;
    const float4* kh4   = (const float4*)(ws + OFF_KHAT);
    const float4* v4    = (const float4*)(ws + OFF_V);
    const float4* vg4   = (const float4*)(ws + OFF_VG);
    float4* plds_flat   = &pair_lds[0][0][0];
    float*  p_s         = (float*)p4_lds;

    // issue chunk 0 -> buf 0 (2 async16/thread; LDS dest lane-linear, global swizzle-permuted)
    #pragma unroll
    for (int it = 0; it < 2; ++it) {
        int idx = it*256 + t;
        int j = idx >> 4, slot = idx & 15;
        int c4 = slot ^ (j & 7);
        async16(pair4 + ((size_t)i*L_SEQ + j)*16 + c4, plds_flat + idx);
    }

    for (int ch = 0; ch < NCH; ++ch) {
        const int cur = ch & 1;
        const int j0 = ch * JC;

        ASYNC_BAR();   // prev iter's reads of buf[1-cur] done; (ch=0: qhat/wbt published)
        if (ch + 1 < NCH) {
            const int jn = (ch + 1) * JC;
            #pragma unroll
            for (int it = 0; it < 2; ++it) {
                int idx = it*256 + t;
                int j = idx >> 4, slot = idx & 15;
                int c4 = slot ^ (j & 7);
                async16(pair4 + ((size_t)i*L_SEQ + jn + j)*16 + c4,
                        plds_flat + (1 - cur)*512 + idx);
            }
            asm volatile("s_waitcnt vmcnt(2)" ::: "memory");   // drain chunk ch, keep ch+1 in flight
        } else {
            asm volatile("s_waitcnt vmcnt(0)" ::: "memory");
        }
        ASYNC_BAR();   // buf[cur] visible to all waves

        // early-issue kh loads (head wv, row j0+j_s, k-half khalf) — latency hides under bias dot
        float4 kh[6];
        {
            const float4* kp = kh4 + (size_t)(j0 + j_s)*48 + wv*12 + khalf*6;
            #pragma unroll
            for (int k4 = 0; k4 < 6; ++k4) kh[k4] = kp[k4];
        }

        float4 vv[4];   // o_s V tiles (issued mid-S, consumed in A)
        float4 gvv[2];  // o_pt_g VG tiles

        // ---- phase S: bias (c-half) + logit (k-half) + combine + online softmax ----
        {
            // bias partial over this lane's 32 c-channels (8 swizzled slots)
            float bias = 0.f;
            #pragma unroll
            for (int cp = 0; cp < 8; ++cp) {
                int c4 = khalf*8 + cp;
                int sw = c4 ^ (j_s & 7);
                float4 pv = pair_lds[cur][j_s][sw];
                float4 wh = wbt_lds[wv][c4];
                bias += pv.x*wh.x + pv.y*wh.y + pv.z*wh.z + pv.w*wh.w;
            }
            // dot partial over this lane's 24 k-slots (2 accumulators shorten dep chain)
            float da = 0.f, db = 0.f;
            #pragma unroll
            for (int k4 = 0; k4 < 6; k4 += 2) {
                float4 q0 = qhat_lds[wv][khalf*6 + k4];
                float4 q1 = qhat_lds[wv][khalf*6 + k4 + 1];
                da = fmaf(kh[k4].x,   q0.x, da); da = fmaf(kh[k4].y,   q0.y, da);
                da = fmaf(kh[k4].z,   q0.z, da); da = fmaf(kh[k4].w,   q0.w, da);
                db = fmaf(kh[k4+1].x, q1.x, db); db = fmaf(kh[k4+1].y, q1.y, db);
                db = fmaf(kh[k4+1].z, q1.z, db); db = fmaf(kh[k4+1].w, q1.w, db);
            }
            float part = da + db + bias;
            float logit = part + __shfl_xor(part, 32);   // combine k/c halves -> full logit, both lanes

            // issue phase-A global loads now (independent of softmax chain; kh dead -> regs reused)
            #pragma unroll
            for (int jj = 0; jj < 4; ++jj)
                vv[jj] = v4[(size_t)(j0 + jg_s + 8*jj)*32 + wv*8 + d4];
            #pragma unroll
            for (int jj = 0; jj < 2; ++jj)
                gvv[jj] = vg4[(size_t)(j0 + jg_g + 16*jj)*12 + wv*3 + g4c];

            float cmax = logit;
            #pragma unroll
            for (int off = 1; off < 32; off <<= 1) cmax = fmaxf(cmax, __shfl_xor(cmax, off));
            float mn = fmaxf(m_run, cmax);
            float alpha = __expf(m_run - mn);
            float p = __expf(logit - mn);
            l_run = l_run * alpha + p;    // both lane-halves accumulate identically; halved at the end
            m_run = mn;
            alpha_own = alpha;
            if (lane < 32) p_s[j_s*4 + wv] = p;
            if (lane == 0) alpha_lds[wv] = alpha;
        }
        ASYNC_BAR();

        // ---- phase A: rescale + accumulate ----
        {
            float al0 = alpha_lds[0], al1 = alpha_lds[1], al2 = alpha_lds[2], al3 = alpha_lds[3];
            accp[0].x *= al0; accp[0].y *= al0; accp[0].z *= al0; accp[0].w *= al0;
            accp[1].x *= al1; accp[1].y *= al1; accp[1].z *= al1; accp[1].w *= al1;
            accp[2].x *= al2; accp[2].y *= al2; accp[2].z *= al2; accp[2].w *= al2;
            accp[3].x *= al3; accp[3].y *= al3; accp[3].z *= al3; accp[3].w *= al3;
            accs.x *= alpha_own; accs.y *= alpha_own; accs.z *= alpha_own; accs.w *= alpha_own;
            accg.x *= alpha_own; accg.y *= alpha_own; accg.z *= alpha_own; accg.w *= alpha_own;

            // o_pair: c4 = c4o + c4p, j = jg_p + 16*jj
            {
                int c4 = c4o + c4p;
                #pragma unroll
                for (int jj = 0; jj < 2; ++jj) {
                    int j = jg_p + 16*jj;
                    int sw = c4 ^ (j & 7);
                    float4 pv = pair_lds[cur][j][sw];
                    float4 pj = p4_lds[j];
                    accp[0].x = fmaf(pj.x, pv.x, accp[0].x); accp[0].y = fmaf(pj.x, pv.y, accp[0].y);
                    accp[0].z = fmaf(pj.x, pv.z, accp[0].z); accp[0].w = fmaf(pj.x, pv.w, accp[0].w);
                    accp[1].x = fmaf(pj.y, pv.x, accp[1].x); accp[1].y = fmaf(pj.y, pv.y, accp[1].y);
                    accp[1].z = fmaf(pj.y, pv.z, accp[1].z); accp[1].w = fmaf(pj.y, pv.w, accp[1].w);
                    accp[2].x = fmaf(pj.z, pv.x, accp[2].x); accp[2].y = fmaf(pj.z, pv.y, accp[2].y);
                    accp[2].z = fmaf(pj.z, pv.z, accp[2].z); accp[2].w = fmaf(pj.z, pv.w, accp[2].w);
                    accp[3].x = fmaf(pj.w, pv.x, accp[3].x); accp[3].y = fmaf(pj.w, pv.y, accp[3].y);
                    accp[3].z = fmaf(pj.w, pv.z, accp[3].z); accp[3].w = fmaf(pj.w, pv.w, accp[3].w);
                }
            }
            // o_s: head wv
            #pragma unroll
            for (int jj = 0; jj < 4; ++jj) {
                int j = jg_s + 8*jj;
                float pa = p_s[j*4 + wv];
                accs.x = fmaf(pa, vv[jj].x, accs.x); accs.y = fmaf(pa, vv[jj].y, accs.y);
                accs.z = fmaf(pa, vv[jj].z, accs.z); accs.w = fmaf(pa, vv[jj].w, accs.w);
            }
            // o_pt_g: head wv
            #pragma unroll
            for (int jj = 0; jj < 2; ++jj) {
                int j = jg_g + 16*jj;
                float pa = p_s[j*4 + wv];
                accg.x = fmaf(pa, gvv[jj].x, accg.x); accg.y = fmaf(pa, gvv[jj].y, accg.y);
                accg.z = fmaf(pa, gvv[jj].z, accg.z); accg.w = fmaf(pa, gvv[jj].w, accg.w);
            }
        }
    }

    // ---- epilogue ----
    #pragma unroll
    for (int h = 0; h < 4; ++h) {
        #pragma unroll
        for (int off = 1; off < 16; off <<= 1) {   // reduce over jg_p = lane&15
            accp[h].x += __shfl_xor(accp[h].x, off);
            accp[h].y += __shfl_xor(accp[h].y, off);
            accp[h].z += __shfl_xor(accp[h].z, off);
            accp[h].w += __shfl_xor(accp[h].w, off);
        }
    }
    #pragma unroll
    for (int off = 8; off < 64; off <<= 1) {       // reduce over jg_s
        accs.x += __shfl_xor(accs.x, off); accs.y += __shfl_xor(accs.y, off);
        accs.z += __shfl_xor(accs.z, off); accs.w += __shfl_xor(accs.w, off);
    }
    #pragma unroll
    for (int off = 4; off < 64; off <<= 1) {       // reduce over jg_g
        accg.x += __shfl_xor(accg.x, off); accg.y += __shfl_xor(accg.y, off);
        accg.z += __shfl_xor(accg.z, off); accg.w += __shfl_xor(accg.w, off);
    }
    #pragma unroll
    for (int off = 1; off < 64; off <<= 1)         // reduce l over all lanes (both halves counted)
        l_run += __shfl_xor(l_run, off);
    if (lane == 0) l_lds[wv] = l_run * 0.5f;       // halves duplicated j-coverage
    __syncthreads();                                // also: all pair_lds reads done -> safe to alias

    // epilogue scratch aliased over pair staging region
    float* scratch = (float*)&pair_lds[0][0][0];
    float* u   = scratch;          // [448] concat buffer
    float* og  = scratch + 448;    // [4][12]
    float* tmp = scratch + 512;    // [128] split-k partial

    float invl[4];
    #pragma unroll
    for (int h = 0; h < 4; ++h) invl[h] = 1.f / l_lds[h];

    if (lane < 8) {
        float sc = invl[wv];
        int base = wv*32 + lane*4;
        u[base+0] = accs.x*sc; u[base+1] = accs.y*sc;
        u[base+2] = accs.z*sc; u[base+3] = accs.w*sc;
    }
    if ((lane & 15) == 0) {
        int c4 = c4o + (lane >> 4);
        #pragma unroll
        for (int h = 0; h < 4; ++h) {
            float sc = invl[h];
            int base = 128 + h*64 + c4*4;
            u[base+0] = accp[h].x*sc; u[base+1] = accp[h].y*sc;
            u[base+2] = accp[h].z*sc; u[base+3] = accp[h].w*sc;
        }
    }
    if (lane < 3) {
        float sc = invl[wv];
        og[wv*12 + lane*4+0] = accg.x*sc; og[wv*12 + lane*4+1] = accg.y*sc;
        og[wv*12 + lane*4+2] = accg.z*sc; og[wv*12 + lane*4+3] = accg.w*sc;
    }
    __syncthreads();

    if (t < 16) {
        int h = t >> 2, p = t & 3;
        float R[3][3], tt[3];
        #pragma unroll
        for (int x = 0; x < 3; ++x) {
            #pragma unroll
            for (int y = 0; y < 3; ++y) R[x][y] = T[i*16 + x*4 + y];
            tt[x] = T[i*16 + x*4 + 3];
        }
        float v0 = og[h*12 + p*3+0] - tt[0];
        float v1 = og[h*12 + p*3+1] - tt[1];
        float v2 = og[h*12 + p*3+2] - tt[2];
        float n2 = 0.f;
        #pragma unroll
        for (int x = 0; x < 3; ++x) {
            float o = R[0][x]*v0 + R[1][x]*v1 + R[2][x]*v2;
            u[384 + h*12 + p*3 + x] = o;
            n2 += o*o;
        }
        u[432 + h*4 + p] = sqrtf(n2);
    }
    __syncthreads();

    // final matmul, split-k across thread halves
    {
        int d = t & 127, khf = t >> 7;
        float acc = 0.f;
        const float4* u4 = (const float4*)u;
        int k0 = khf * 56;
        #pragma unroll 4
        for (int k4 = k0; k4 < k0 + 56; ++k4) {
            float4 uu = u4[k4];
            const float* wp = Wout + (size_t)(k4*4)*128 + d;
            acc = fmaf(uu.x, wp[0],   acc);
            acc = fmaf(uu.y, wp[128], acc);
            acc = fmaf(uu.z, wp[256], acc);
            acc = fmaf(uu.w, wp[384], acc);
        }
        if (khf) tmp[d] = acc;
        __syncthreads();
        if (!khf) out[i*DM + d] = single[i*DM + d] + b_out[d] + acc + tmp[d];
    }
}

extern "C" void kernel_launch(void* const* d_in, const int* in_sizes, int n_in,
                              void* d_out, int out_size, void* d_ws, size_t ws_size,
                              hipStream_t stream)
{
    const float* single = (const float*)d_in[0];
    const float* pair   = (const float*)d_in[1];
    const float* T      = (const float*)d_in[2];
    const float* w_C    = (const float*)d_in[3];
    const float* ln_g   = (const float*)d_in[4];
    const float* ln_b   = (const float*)d_in[5];
    const float* Wq     = (const float*)d_in[6];
    const float* Wk     = (const float*)d_in[7];
    const float* Wv     = (const float*)d_in[8];
    const float* Wqpt   = (const float*)d_in[9];
    const float* Wkpt   = (const float*)d_in[10];
    const float* Wvpt   = (const float*)d_in[11];
    const float* Wb     = (const float*)d_in[12];
    const float* Wout   = (const float*)d_in[13];
    const float* b_out  = (const float*)d_in[14];
    float* out = (float*)d_out;
    float* ws  = (float*)d_ws;

    ipa_prep<<<256, 256, 0, stream>>>(single, T, w_C, ln_g, ln_b, Wq, Wk, Wv, Wqpt, Wkpt, Wvpt, ws);
    ipa_attn<<<1024, 256, 0, stream>>>(single, pair, T, Wb, Wout, b_out, ws, out);
}

// Round 4
// 491.874 us; speedup vs baseline: 1.2731x; 1.1009x over previous
//
#include <hip/hip_runtime.h>
#include <math.h>

#define L_SEQ 1024
#define DM 128

// workspace layout (floats)
#define OFF_KHAT 0                         // [L][4][48]  slots: 0..31 K, 32..43 Kg, 44 ck, 45 1.0, 46..47 0
#define OFF_QHAT (L_SEQ * 192)             // [L][4][48]  slots: 0..31 scale*Q, 32..43 w*Qg, 44 1.0, 45 cq
#define OFF_V    (OFF_QHAT + L_SEQ * 192)  // [L][128]    (h*32+d)
#define OFF_VG   (OFF_V + L_SEQ * DM)      // [L][48]     (h*12+p*3+x)

typedef __attribute__((address_space(1))) const void* gas_t;
typedef __attribute__((address_space(3))) void* las_t;

__device__ __forceinline__ void async16(const float4* g, float4* l) {
    __builtin_amdgcn_global_load_lds((gas_t)g, (las_t)l, 16, 0, 0);
}

// ---------------- kernel 1: LN + projections + rotations + staging (1 row/block, grid=1024) ----------------
__global__ __launch_bounds__(256) void ipa_prep(
    const float* __restrict__ single, const float* __restrict__ T,
    const float* __restrict__ w_C, const float* __restrict__ ln_g, const float* __restrict__ ln_b,
    const float* __restrict__ Wq, const float* __restrict__ Wk, const float* __restrict__ Wv,
    const float* __restrict__ Wqpt, const float* __restrict__ Wkpt, const float* __restrict__ Wvpt,
    float* __restrict__ ws)
{
    __shared__ float z_lds[128];
    __shared__ float proj[528];
    __shared__ float qg[4][4][3];
    __shared__ float kg[4][4][3];
    __shared__ float cq[4], ck[4];

    const int t = threadIdx.x;
    const int i = blockIdx.x;

    if (t < 64) {  // wave 0: LayerNorm of row i
        float x0 = single[i*DM + t];
        float x1 = single[i*DM + 64 + t];
        float s = x0 + x1, s2 = x0*x0 + x1*x1;
        #pragma unroll
        for (int off = 1; off < 64; off <<= 1) { s += __shfl_xor(s, off); s2 += __shfl_xor(s2, off); }
        float mu = s * 0.0078125f;
        float var = s2 * 0.0078125f - mu*mu;
        float rs = rsqrtf(var + 1e-5f);
        z_lds[t]      = (x0 - mu) * rs * ln_g[t]      + ln_b[t];
        z_lds[t + 64] = (x1 - mu) * rs * ln_g[t + 64] + ln_b[t + 64];
    }
    __syncthreads();

    for (int cc = t; cc < 528; cc += 256) {
        const float* W; int col, ncol;
        if (cc < 128)      { W = Wq;   col = cc;       ncol = 128; }
        else if (cc < 256) { W = Wk;   col = cc - 128; ncol = 128; }
        else if (cc < 384) { W = Wv;   col = cc - 256; ncol = 128; }
        else if (cc < 432) { W = Wqpt; col = cc - 384; ncol = 48;  }
        else if (cc < 480) { W = Wkpt; col = cc - 432; ncol = 48;  }
        else               { W = Wvpt; col = cc - 480; ncol = 48;  }
        float a = 0.f;
        #pragma unroll 8
        for (int k = 0; k < 128; ++k)
            a = fmaf(z_lds[k], W[k*ncol + col], a);
        proj[cc] = a;
    }
    __syncthreads();

    if (t < 16) {
        int h = t >> 2, p = t & 3;
        float R[3][3], tt[3];
        #pragma unroll
        for (int x = 0; x < 3; ++x) {
            #pragma unroll
            for (int y = 0; y < 3; ++y) R[x][y] = T[i*16 + x*4 + y];
            tt[x] = T[i*16 + x*4 + 3];
        }
        int base = 384 + (h*4 + p)*3;
        float q0 = proj[base],    q1 = proj[base+1],  q2 = proj[base+2];
        float k0 = proj[base+48], k1 = proj[base+49], k2 = proj[base+50];
        float v0 = proj[base+96], v1 = proj[base+97], v2 = proj[base+98];
        #pragma unroll
        for (int x = 0; x < 3; ++x) {
            float qq = R[x][0]*q0 + R[x][1]*q1 + R[x][2]*q2 + tt[x];
            float kk = R[x][0]*k0 + R[x][1]*k1 + R[x][2]*k2 + tt[x];
            float vv = R[x][0]*v0 + R[x][1]*v1 + R[x][2]*v2 + tt[x];
            qg[h][p][x] = qq;
            kg[h][p][x] = kk;
            ws[OFF_VG + (size_t)i*48 + h*12 + p*3 + x] = vv;
        }
    }
    __syncthreads();

    if (t < 8) {
        int h = t >> 1, isk = t & 1;
        float w = w_C[h];
        float wp = log1pf(__expf(w));
        float sq = 0.f;
        #pragma unroll
        for (int p = 0; p < 4; ++p)
            #pragma unroll
            for (int x = 0; x < 3; ++x) {
                float g = isk ? kg[h][p][x] : qg[h][p][x];
                sq += g*g;
            }
        float c = -0.5f * wp * sq;
        if (isk) ck[h] = c; else cq[h] = c;
    }
    __syncthreads();

    if (t < 128) ws[OFF_V + (size_t)i*DM + t] = proj[256 + t];
    const float scale_attn = 0.17677669529663687f;  // 32^-0.5
    if (t < 192) {
        int h = t / 48, k = t % 48;
        float w = w_C[h];
        float wp = log1pf(__expf(w));
        float kv, qv;
        if (k < 32) {
            kv = proj[128 + h*32 + k];
            qv = scale_attn * proj[h*32 + k];
        } else if (k < 44) {
            int e = k - 32;
            kv = kg[h][e/3][e%3];
            qv = wp * qg[h][e/3][e%3];
        } else if (k == 44) { kv = ck[h]; qv = 1.0f; }
        else if (k == 45)   { kv = 1.0f; qv = cq[h]; }
        else                { kv = 0.f;  qv = 0.f; }
        ws[OFF_KHAT + (size_t)i*192 + t] = kv;
        ws[OFF_QHAT + (size_t)i*192 + t] = qv;
    }
}

// ---------------- kernel 2: wave-autonomous flash IPA; NO barriers in main loop ----------------
// Each wave owns j-quarter [wv*256, wv*256+256), 16 steps x 16 j. Own LDS pair dbuf, own vmcnt.
// End: split-j softmax combine across the 4 waves (5 barriers total).
__global__ __launch_bounds__(256, 2) void ipa_attn(
    const float* __restrict__ single, const float* __restrict__ pair,
    const float* __restrict__ T, const float* __restrict__ Wb,
    const float* __restrict__ Wout, const float* __restrict__ b_out,
    const float* __restrict__ ws, float* __restrict__ out)
{
    // LDS: 32768 + 832 + 1088 + 1024 = 35712 B -> 4 blocks/CU
    __shared__ __align__(16) float4 pair_w[4][2][16][16]; // [wave][buf][j][slot], slot = c4 ^ (j&7)
    __shared__ __align__(16) float4 qhat_lds[4][13];      // [h][k4] pad 13 (bank spread)
    __shared__ __align__(16) float wbt_lds[4][68];        // Wb^T [h][c] pad 68 (16B-aligned: float4 reads)
    __shared__ __align__(16) float p_ws[4][16][4];        // [wave][j][h] (16B-aligned: float4 reads)

    const int t = threadIdx.x;
    const int wv = t >> 6, lane = t & 63;
    const int i = blockIdx.x;

    if (t < 48) {
        int h = t / 12, k4 = t % 12;
        qhat_lds[h][k4] = ((const float4*)(ws + OFF_QHAT))[(size_t)i*48 + t];
    } else if (t < 112) {
        int c = t - 48;
        float4 w4 = ((const float4*)Wb)[c];   // Wb[c][0..3]
        wbt_lds[0][c] = w4.x; wbt_lds[1][c] = w4.y; wbt_lds[2][c] = w4.z; wbt_lds[3][c] = w4.w;
    }

    // roles within the wave
    const int m_h  = lane & 3,  m_j  = lane >> 2;          // softmax: 16 j x 4 h
    const int os_h = lane >> 4, os_jh = (lane >> 3) & 1, os_d4 = lane & 7;  // o_s
    const int op_c4 = lane & 15, op_jq = lane >> 4;        // o_pair
    const int og_he = lane & 15, og_jq = lane >> 4;        // o_pt_g (he = float4-group, active he<12)
    const bool og_act = og_he < 12;
    const int og_h  = (og_act ? og_he : 0) / 3;
    const int og_ix = og_act ? og_he : 0;

    float m_run = -INFINITY, l_run = 0.f;
    float4 accp[4];
    float4 accs = make_float4(0.f,0.f,0.f,0.f);
    float4 accg = make_float4(0.f,0.f,0.f,0.f);
    #pragma unroll
    for (int h = 0; h < 4; ++h) accp[h] = make_float4(0.f,0.f,0.f,0.f);

    const float4* pair4 = (const float4*)pair;
    const float4* kh4   = (const float4*)(ws + OFF_KHAT);
    const float4* v4    = (const float4*)(ws + OFF_V);
    const float4* vg4   = (const float4*)(ws + OFF_VG);
    float4* mypair = &pair_w[wv][0][0][0];
    const size_t prow_base = (size_t)i*L_SEQ + wv*256;

    // prologue: stage step 0 -> buf 0 (4 async16/lane; LDS lane-linear, global swizzle-permuted)
    #pragma unroll
    for (int it = 0; it < 4; ++it) {
        int idx = it*64 + lane;
        int j = idx >> 4, slot = idx & 15;
        int c4 = slot ^ (j & 7);
        async16(pair4 + (prow_base + j)*16 + c4, mypair + idx);
    }
    __syncthreads();   // qhat/wbt published (also drains stage 0)

    for (int s = 0; s < 16; ++s) {
        const int cur = s & 1;
        const int j0 = wv*256 + s*16;

        // (1) kh loads first (retire before the stage ops issued below)
        float4 kh[12];
        {
            const float4* kp = kh4 + (size_t)(j0 + m_j)*48 + m_h*12;
            #pragma unroll
            for (int k4 = 0; k4 < 12; ++k4) kh[k4] = kp[k4];
        }
        // (2) issue next stage, then drain this step's buffer (in-order retirement:
        //     waiting to <=16 outstanding retires the 4 oldest = stage s when 20 in flight)
        if (s + 1 < 16) {
            #pragma unroll
            for (int it = 0; it < 4; ++it) {
                int idx = it*64 + lane;
                int j = idx >> 4, slot = idx & 15;
                int c4 = slot ^ (j & 7);
                async16(pair4 + (prow_base + (s+1)*16 + j)*16 + c4,
                        mypair + (1 - cur)*256 + idx);
            }
            asm volatile("s_waitcnt vmcnt(16)" ::: "memory");
        } else {
            asm volatile("s_waitcnt vmcnt(12)" ::: "memory");
        }

        // (3) bias (64-c dot) + logit (48-dot), lane = (m_j, m_h)
        const float4* prow = mypair + cur*256 + m_j*16;
        const float4* wrow = (const float4*)&wbt_lds[m_h][0];
        float bias = 0.f;
        #pragma unroll
        for (int cc = 0; cc < 16; ++cc) {
            int sw = cc ^ (m_j & 7);
            float4 pv = prow[sw];     // channel-quad cc (swizzled slot)
            float4 wh = wrow[cc];     // Wb channels cc*4.. for head m_h (broadcast)
            bias += pv.x*wh.x + pv.y*wh.y + pv.z*wh.z + pv.w*wh.w;
        }
        float da = 0.f, db = 0.f;
        #pragma unroll
        for (int k4 = 0; k4 < 12; k4 += 2) {
            float4 qa = qhat_lds[m_h][k4], qb = qhat_lds[m_h][k4+1];
            da = fmaf(kh[k4].x,   qa.x, da); da = fmaf(kh[k4].y,   qa.y, da);
            da = fmaf(kh[k4].z,   qa.z, da); da = fmaf(kh[k4].w,   qa.w, da);
            db = fmaf(kh[k4+1].x, qb.x, db); db = fmaf(kh[k4+1].y, qb.y, db);
            db = fmaf(kh[k4+1].z, qb.z, db); db = fmaf(kh[k4+1].w, qb.w, db);
        }
        float logit = da + db + bias;

        // (4) online softmax over the wave's 16 j's (per head; j-lanes stride 4)
        float cmax = logit;
        cmax = fmaxf(cmax, __shfl_xor(cmax, 4));
        cmax = fmaxf(cmax, __shfl_xor(cmax, 8));
        cmax = fmaxf(cmax, __shfl_xor(cmax, 16));
        cmax = fmaxf(cmax, __shfl_xor(cmax, 32));
        float mn = fmaxf(m_run, cmax);
        float alpha = __expf(m_run - mn);
        float p = __expf(logit - mn);
        l_run = l_run * alpha + p;
        m_run = mn;
        p_ws[wv][m_j][m_h] = p;
        float a0 = __shfl(alpha, 0), a1 = __shfl(alpha, 1);
        float a2 = __shfl(alpha, 2), a3 = __shfl(alpha, 3);
        asm volatile("" ::: "memory");   // order p_ws write before cross-lane reads (DS in-order per wave)

        // (5) rescale + accumulate
        accp[0].x *= a0; accp[0].y *= a0; accp[0].z *= a0; accp[0].w *= a0;
        accp[1].x *= a1; accp[1].y *= a1; accp[1].z *= a1; accp[1].w *= a1;
        accp[2].x *= a2; accp[2].y *= a2; accp[2].z *= a2; accp[2].w *= a2;
        accp[3].x *= a3; accp[3].y *= a3; accp[3].z *= a3; accp[3].w *= a3;
        float aa_s = (os_h & 2) ? ((os_h & 1) ? a3 : a2) : ((os_h & 1) ? a1 : a0);
        float aa_g = (og_h & 2) ? ((og_h & 1) ? a3 : a2) : ((og_h & 1) ? a1 : a0);
        accs.x *= aa_s; accs.y *= aa_s; accs.z *= aa_s; accs.w *= aa_s;
        accg.x *= aa_g; accg.y *= aa_g; accg.z *= aa_g; accg.w *= aa_g;

        // o_pair: lane (c4, jq), 4 j's
        #pragma unroll
        for (int jj = 0; jj < 4; ++jj) {
            int j = op_jq*4 + jj;
            int sw = op_c4 ^ (j & 7);
            float4 pv = mypair[cur*256 + j*16 + sw];
            float4 pj = *(const float4*)&p_ws[wv][j][0];
            accp[0].x = fmaf(pj.x, pv.x, accp[0].x); accp[0].y = fmaf(pj.x, pv.y, accp[0].y);
            accp[0].z = fmaf(pj.x, pv.z, accp[0].z); accp[0].w = fmaf(pj.x, pv.w, accp[0].w);
            accp[1].x = fmaf(pj.y, pv.x, accp[1].x); accp[1].y = fmaf(pj.y, pv.y, accp[1].y);
            accp[1].z = fmaf(pj.y, pv.z, accp[1].z); accp[1].w = fmaf(pj.y, pv.w, accp[1].w);
            accp[2].x = fmaf(pj.z, pv.x, accp[2].x); accp[2].y = fmaf(pj.z, pv.y, accp[2].y);
            accp[2].z = fmaf(pj.z, pv.z, accp[2].z); accp[2].w = fmaf(pj.z, pv.w, accp[2].w);
            accp[3].x = fmaf(pj.w, pv.x, accp[3].x); accp[3].y = fmaf(pj.w, pv.y, accp[3].y);
            accp[3].z = fmaf(pj.w, pv.z, accp[3].z); accp[3].w = fmaf(pj.w, pv.w, accp[3].w);
        }
        // o_s: lane (h, jh, d4), 8 j's
        #pragma unroll
        for (int jj = 0; jj < 8; ++jj) {
            int j = os_jh*8 + jj;
            float4 vvv = v4[(size_t)(j0 + j)*32 + os_h*8 + os_d4];
            float pa = p_ws[wv][j][os_h];
            accs.x = fmaf(pa, vvv.x, accs.x); accs.y = fmaf(pa, vvv.y, accs.y);
            accs.z = fmaf(pa, vvv.z, accs.z); accs.w = fmaf(pa, vvv.w, accs.w);
        }
        // o_pt_g: lane (he, jq), 4 j's
        #pragma unroll
        for (int jj = 0; jj < 4; ++jj) {
            int j = og_jq*4 + jj;
            float4 gv = vg4[(size_t)(j0 + j)*12 + og_ix];
            float pa = og_act ? p_ws[wv][j][og_h] : 0.f;
            accg.x = fmaf(pa, gv.x, accg.x); accg.y = fmaf(pa, gv.y, accg.y);
            accg.z = fmaf(pa, gv.z, accg.z); accg.w = fmaf(pa, gv.w, accg.w);
        }
    }

    // ---- intra-wave reductions ----
    l_run += __shfl_xor(l_run, 4);  l_run += __shfl_xor(l_run, 8);
    l_run += __shfl_xor(l_run, 16); l_run += __shfl_xor(l_run, 32);
    #pragma unroll
    for (int h = 0; h < 4; ++h) {
        #pragma unroll
        for (int off = 16; off < 64; off <<= 1) {
            accp[h].x += __shfl_xor(accp[h].x, off);
            accp[h].y += __shfl_xor(accp[h].y, off);
            accp[h].z += __shfl_xor(accp[h].z, off);
            accp[h].w += __shfl_xor(accp[h].w, off);
        }
    }
    accs.x += __shfl_xor(accs.x, 8); accs.y += __shfl_xor(accs.y, 8);
    accs.z += __shfl_xor(accs.z, 8); accs.w += __shfl_xor(accs.w, 8);
    #pragma unroll
    for (int off = 16; off < 64; off <<= 1) {
        accg.x += __shfl_xor(accg.x, off); accg.y += __shfl_xor(accg.y, off);
        accg.z += __shfl_xor(accg.z, off); accg.w += __shfl_xor(accg.w, off);
    }

    // ---- publish per-wave partials into own pair region (buf 0 half; last step read buf 1) ----
    float* scratch = (float*)&pair_w[0][0][0][0];
    float* cw = scratch + wv*2048;   // wave's 8KB region
    if (lane < 16) {
        #pragma unroll
        for (int h = 0; h < 4; ++h)
            *(float4*)&cw[h*64 + op_c4*4] = accp[h];
    }
    if (os_jh == 0) *(float4*)&cw[256 + os_h*32 + os_d4*4] = accs;
    if (lane < 12)  *(float4*)&cw[384 + lane*4] = accg;
    if (lane < 4)   { cw[432 + lane] = l_run; cw[436 + lane] = m_run; }
    __syncthreads();

    // epilogue scratch (wave0 buf1 half: floats 1024..2047 — all pair reads done)
    float* u    = scratch + 1024;  // [448]
    float* og   = scratch + 1536;  // [48]
    float* tmp  = scratch + 1600;  // [128]
    float* wtS  = scratch + 1728;  // [16] w*4+h
    float* invS = scratch + 1744;  // [4]

    if (t < 4) {
        int h = t;
        float m0 = scratch[436 + h],        m1 = scratch[2048 + 436 + h];
        float m2 = scratch[4096 + 436 + h], m3 = scratch[6144 + 436 + h];
        float M = fmaxf(fmaxf(m0, m1), fmaxf(m2, m3));
        float w0 = __expf(m0 - M), w1 = __expf(m1 - M);
        float w2 = __expf(m2 - M), w3 = __expf(m3 - M);
        float L = scratch[432+h]*w0 + scratch[2048+432+h]*w1
                + scratch[4096+432+h]*w2 + scratch[6144+432+h]*w3;
        wtS[h] = w0; wtS[4+h] = w1; wtS[8+h] = w2; wtS[12+h] = w3;
        invS[h] = 1.f / L;
    }
    __syncthreads();

    {
        int hp = t >> 6;   // o_pair head
        float sum = scratch[t]*wtS[hp] + scratch[2048+t]*wtS[4+hp]
                  + scratch[4096+t]*wtS[8+hp] + scratch[6144+t]*wtS[12+hp];
        u[128 + t] = sum * invS[hp];
        if (t < 128) {
            int hs = t >> 5;
            float ssum = scratch[256+t]*wtS[hs] + scratch[2048+256+t]*wtS[4+hs]
                       + scratch[4096+256+t]*wtS[8+hs] + scratch[6144+256+t]*wtS[12+hs];
            u[t] = ssum * invS[hs];
        }
        if (t < 48) {
            int hg = t / 12;
            float gsum = scratch[384+t]*wtS[hg] + scratch[2048+384+t]*wtS[4+hg]
                       + scratch[4096+384+t]*wtS[8+hg] + scratch[6144+384+t]*wtS[12+hg];
            og[t] = gsum * invS[hg];
        }
    }
    __syncthreads();

    if (t < 16) {
        int h = t >> 2, p = t & 3;
        float R[3][3], tt[3];
        #pragma unroll
        for (int x = 0; x < 3; ++x) {
            #pragma unroll
            for (int y = 0; y < 3; ++y) R[x][y] = T[i*16 + x*4 + y];
            tt[x] = T[i*16 + x*4 + 3];
        }
        float v0 = og[h*12 + p*3+0] - tt[0];
        float v1 = og[h*12 + p*3+1] - tt[1];
        float v2 = og[h*12 + p*3+2] - tt[2];
        float n2 = 0.f;
        #pragma unroll
        for (int x = 0; x < 3; ++x) {
            float o = R[0][x]*v0 + R[1][x]*v1 + R[2][x]*v2;
            u[384 + h*12 + p*3 + x] = o;
            n2 += o*o;
        }
        u[432 + h*4 + p] = sqrtf(n2);
    }
    __syncthreads();

    // final matmul, split-k across thread halves
    {
        int d = t & 127, khf = t >> 7;
        float acc = 0.f;
        const float4* u4 = (const float4*)u;
        int k0 = khf * 56;
        #pragma unroll 4
        for (int k4 = k0; k4 < k0 + 56; ++k4) {
            float4 uu = u4[k4];
            const float* wp = Wout + (size_t)(k4*4)*128 + d;
            acc = fmaf(uu.x, wp[0],   acc);
            acc = fmaf(uu.y, wp[128], acc);
            acc = fmaf(uu.z, wp[256], acc);
            acc = fmaf(uu.w, wp[384], acc);
        }
        if (khf) tmp[d] = acc;
        __syncthreads();
        if (!khf) out[i*DM + d] = single[i*DM + d] + b_out[d] + acc + tmp[d];
    }
}

extern "C" void kernel_launch(void* const* d_in, const int* in_sizes, int n_in,
                              void* d_out, int out_size, void* d_ws, size_t ws_size,
                              hipStream_t stream)
{
    const float* single = (const float*)d_in[0];
    const float* pair   = (const float*)d_in[1];
    const float* T      = (const float*)d_in[2];
    const float* w_C    = (const float*)d_in[3];
    const float* ln_g   = (const float*)d_in[4];
    const float* ln_b   = (const float*)d_in[5];
    const float* Wq     = (const float*)d_in[6];
    const float* Wk     = (const float*)d_in[7];
    const float* Wv     = (const float*)d_in[8];
    const float* Wqpt   = (const float*)d_in[9];
    const float* Wkpt   = (const float*)d_in[10];
    const float* Wvpt   = (const float*)d_in[11];
    const float* Wb     = (const float*)d_in[12];
    const float* Wout   = (const float*)d_in[13];
    const float* b_out  = (const float*)d_in[14];
    float* out = (float*)d_out;
    float* ws  = (float*)d_ws;

    ipa_prep<<<1024, 256, 0, stream>>>(single, T, w_C, ln_g, ln_b, Wq, Wk, Wv, Wqpt, Wkpt, Wvpt, ws);
    ipa_attn<<<1024, 256, 0, stream>>>(single, pair, T, Wb, Wout, b_out, ws, out);
}